// Round 3
// baseline (376.991 us; speedup 1.0000x reference)
//
#include <hip/hip_runtime.h>

// Problem constants (match reference)
constexpr int B = 16, N = 16, H = 512, W = 512;
constexpr int HW = H * W;            // 262144
constexpr int S = 8;                 // chunks per (b,n) plane
constexpr int CHUNK = HW / S;        // 32768 elements (128 KB)
constexpr int THREADS = 256;
constexpr int NP = B * N * S;        // 2048 partial blocks

// Each block reduces one (b,n,s) chunk and writes 3 partials to unique ws
// slots — no atomics, no memset. 2048 blocks / 256 CUs = 8 blocks/CU for
// dispatch self-balancing.
__global__ __launch_bounds__(THREADS) void partial_kernel(
    const float* __restrict__ masks,   // (B,N,H,W)
    const float* __restrict__ target,  // (B,H,W)
    const int*   __restrict__ boxes,   // (B,N,4) xyxy
    float* __restrict__ ws)            // 3 * NP floats
{
    // blk = ((b*S + s)*N + n): n innermost → the 16 blocks sharing a
    // target[b] chunk are dispatch-adjacent (L2 locality).
    const int blk = blockIdx.x;
    const int n  = blk % N;
    const int bs = blk / N;
    const int s  = bs % S;
    const int b  = bs / S;
    const int bn = b * N + n;

    const int x1 = boxes[bn * 4 + 0];
    const int y1 = boxes[bn * 4 + 1];
    const int x2 = boxes[bn * 4 + 2];
    const int y2 = boxes[bn * 4 + 3];

    const float4* m4 = (const float4*)(masks + (size_t)bn * HW + (size_t)s * CHUNK);
    const float4* t4 = (const float4*)(target + (size_t)b * HW + (size_t)s * CHUNK);
    const int base_idx = s * CHUNK;

    float ov = 0.f, inter = 0.f, ts = 0.f;
    // CHUNK/4 = 8192 float4s; 32 iters/thread, 16 B/lane coalesced.
    #pragma unroll 4
    for (int i = threadIdx.x; i < CHUNK / 4; i += THREADS) {
        float4 m = m4[i];
        float4 t = t4[i];
        ov += m.x * t.x + m.y * t.y + m.z * t.z + m.w * t.w;
        ts += t.x + t.y + t.z + t.w;
        int idx = base_idx + i * 4;
        int h = idx >> 9;          // / W (512)
        int w = idx & (W - 1);     // % W, 4-aligned, row never crossed
        if (h >= y1 && h < y2) {
            if (w     >= x1 && w     < x2) inter += t.x;
            if (w + 1 >= x1 && w + 1 < x2) inter += t.y;
            if (w + 2 >= x1 && w + 2 < x2) inter += t.z;
            if (w + 3 >= x1 && w + 3 < x2) inter += t.w;
        }
    }

    // wave(64) shuffle reduction, then cross-wave via LDS
    for (int off = 32; off > 0; off >>= 1) {
        ov    += __shfl_down(ov, off);
        inter += __shfl_down(inter, off);
        ts    += __shfl_down(ts, off);
    }
    __shared__ float red[3][THREADS / 64];
    const int wave = threadIdx.x >> 6;
    if ((threadIdx.x & 63) == 0) {
        red[0][wave] = ov;
        red[1][wave] = inter;
        red[2][wave] = ts;
    }
    __syncthreads();
    if (threadIdx.x == 0) {
        ws[0 * NP + blk] = red[0][0] + red[0][1] + red[0][2] + red[0][3];
        ws[1 * NP + blk] = red[1][0] + red[1][1] + red[1][2] + red[1][3];
        ws[2 * NP + blk] = red[2][0] + red[2][1] + red[2][2] + red[2][3];
    }
}

__global__ __launch_bounds__(B * N) void finalize_kernel(
    const int*   __restrict__ boxes,
    const float* __restrict__ ws,
    float* __restrict__ out)   // (B,N,2)
{
    const int bn = threadIdx.x;   // one thread per (b,n)
    const int b = bn >> 4;        // N = 16
    const int n = bn & 15;
    float ov = 0.f, inter = 0.f, ts = 0.f;
    #pragma unroll
    for (int s = 0; s < S; ++s) {
        int blk = (b * S + s) * N + n;
        ov    += ws[0 * NP + blk];
        inter += ws[1 * NP + blk];
        ts    += ws[2 * NP + blk];
    }
    int x1 = boxes[bn * 4 + 0], y1 = boxes[bn * 4 + 1];
    int x2 = boxes[bn * 4 + 2], y2 = boxes[bn * 4 + 3];
    int bw = min(x2, W) - max(x1, 0); if (bw < 0) bw = 0;
    int bh = min(y2, H) - max(y1, 0); if (bh < 0) bh = 0;
    float box_area = (float)bw * (float)bh;
    float uni = box_area + ts - inter;
    out[bn * 2 + 0] = ov;
    out[bn * 2 + 1] = inter / (uni + 1e-8f);
}

extern "C" void kernel_launch(void* const* d_in, const int* in_sizes, int n_in,
                              void* d_out, int out_size, void* d_ws, size_t ws_size,
                              hipStream_t stream) {
    const float* masks  = (const float*)d_in[0];   // (B,N,H,W) fp32
    const float* target = (const float*)d_in[1];   // (B,H,W)   fp32
    const int*   boxes  = (const int*)d_in[2];     // (B,N,4)   int32
    float* out = (float*)d_out;
    float* ws  = (float*)d_ws;   // every slot written; no memset needed

    partial_kernel<<<NP, THREADS, 0, stream>>>(masks, target, boxes, ws);
    finalize_kernel<<<1, B * N, 0, stream>>>(boxes, ws, out);
}

// Round 5
// 358.032 us; speedup vs baseline: 1.0530x; 1.0530x over previous
//
#include <hip/hip_runtime.h>

// Problem constants (match reference)
constexpr int B = 16, N = 16, H = 512, W = 512;
constexpr int HW = H * W;            // 262144
constexpr int THREADS = 1024;        // 16 waves/block, grid = 256 = 1 block/CU
constexpr int NWAVE = THREADS / 64;

// Native clang vector type — __builtin_nontemporal_load needs this (HIP's
// float4 is a class and is rejected).
typedef float floatx4 __attribute__((ext_vector_type(4)));

// One block per (b,n): streams masks[b,n] (1 MB, non-temporal) and target[b]
// (1 MB, L2-resident via XCD-aware remap), computes overlap, box∩target and
// target_area in one pass, finalizes IoU in-block. No workspace, no atomics.
__global__ __launch_bounds__(THREADS) void fused_kernel(
    const float* __restrict__ masks,   // (B,N,H,W)
    const float* __restrict__ target,  // (B,H,W)
    const int*   __restrict__ boxes,   // (B,N,4) xyxy
    float* __restrict__ out)           // (B,N,2)
{
    // XCD-aware remap: HW dispatch round-robins block i -> XCD (i & 7).
    // Map so all 16 n-blocks of a given b land on ONE XCD (2 b's per XCD,
    // 32 blocks = that XCD's 32 CUs): target[b] (1 MB) stays resident in the
    // XCD's 4 MiB L2 instead of being replicated into all 8 L2s.
    const int i0   = blockIdx.x;
    const int xcd  = i0 & 7;
    const int slot = i0 >> 3;              // 0..31
    const int b    = xcd * 2 + (slot >> 4);
    const int n    = slot & 15;
    const int bn   = b * N + n;

    const int x1 = boxes[bn * 4 + 0];
    const int y1 = boxes[bn * 4 + 1];
    const int x2 = boxes[bn * 4 + 2];
    const int y2 = boxes[bn * 4 + 3];

    const floatx4* m4 = (const floatx4*)(masks + (size_t)bn * HW);
    const floatx4* t4 = (const floatx4*)(target + (size_t)b * HW);

    float ov = 0.f, inter = 0.f, ts = 0.f;
    // HW/4 = 65536 float4s; 64 iters/thread, 16 B/lane coalesced.
    // masks: streamed exactly once -> non-temporal (don't evict target in L2).
    #pragma unroll 8
    for (int i = threadIdx.x; i < HW / 4; i += THREADS) {
        floatx4 m = __builtin_nontemporal_load(&m4[i]);
        floatx4 t = t4[i];
        ov += m.x * t.x + m.y * t.y + m.z * t.z + m.w * t.w;
        ts += t.x + t.y + t.z + t.w;
        int h = i >> 7;            // (i*4) / W, W = 512
        int w = (i & 127) << 2;    // (i*4) % W, 4-aligned, row never crossed
        if (h >= y1 && h < y2) {
            if (w     >= x1 && w     < x2) inter += t.x;
            if (w + 1 >= x1 && w + 1 < x2) inter += t.y;
            if (w + 2 >= x1 && w + 2 < x2) inter += t.z;
            if (w + 3 >= x1 && w + 3 < x2) inter += t.w;
        }
    }

    // wave(64) shuffle reduction, then cross-wave via LDS
    for (int off = 32; off > 0; off >>= 1) {
        ov    += __shfl_down(ov, off);
        inter += __shfl_down(inter, off);
        ts    += __shfl_down(ts, off);
    }
    __shared__ float red[3][NWAVE];
    const int wave = threadIdx.x >> 6;
    if ((threadIdx.x & 63) == 0) {
        red[0][wave] = ov;
        red[1][wave] = inter;
        red[2][wave] = ts;
    }
    __syncthreads();
    if (threadIdx.x == 0) {
        float o = 0.f, it = 0.f, t = 0.f;
        #pragma unroll
        for (int k = 0; k < NWAVE; ++k) { o += red[0][k]; it += red[1][k]; t += red[2][k]; }
        int bw = min(x2, W) - max(x1, 0); if (bw < 0) bw = 0;
        int bh = min(y2, H) - max(y1, 0); if (bh < 0) bh = 0;
        float box_area = (float)bw * (float)bh;
        float uni = box_area + t - it;
        out[bn * 2 + 0] = o;
        out[bn * 2 + 1] = it / (uni + 1e-8f);
    }
}

extern "C" void kernel_launch(void* const* d_in, const int* in_sizes, int n_in,
                              void* d_out, int out_size, void* d_ws, size_t ws_size,
                              hipStream_t stream) {
    const float* masks  = (const float*)d_in[0];   // (B,N,H,W) fp32
    const float* target = (const float*)d_in[1];   // (B,H,W)   fp32
    const int*   boxes  = (const int*)d_in[2];     // (B,N,4)   int32
    float* out = (float*)d_out;

    fused_kernel<<<B * N, THREADS, 0, stream>>>(masks, target, boxes, out);
}